// Round 12
// baseline (1532.241 us; speedup 1.0000x reference)
//
#include <hip/hip_runtime.h>

#define EDGES 200000
#define NATOMS 100000
#define NMOLS 2000
#define H 128
#define MAXNB 15
#define AFD 18
#define INFD 23

typedef unsigned short bf16s;
typedef __attribute__((ext_vector_type(8))) short short8;
typedef __attribute__((ext_vector_type(8))) unsigned short ushort8v;
typedef __attribute__((ext_vector_type(4))) float f32x4;

__device__ inline float bf2f(bf16s u) {
  union { unsigned int i; float f; } c; c.i = ((unsigned int)u) << 16; return c.f;
}
__device__ inline bf16s f2bf(float f) {
  union { float f; unsigned int i; } c; c.f = f;
  unsigned int lsb = (c.i >> 16) & 1u;
  c.i += 0x7fffu + lsb;              // round-to-nearest-even
  return (bf16s)(c.i >> 16);
}
__device__ inline void load4(const bf16s* p, float v[4]) {
  ushort4 t = *(const ushort4*)p;
  v[0] = bf2f(t.x); v[1] = bf2f(t.y); v[2] = bf2f(t.z); v[3] = bf2f(t.w);
}

// ------- one-time: Wt[n][k] = bf16(W[k][n]) for W_h and W_o[AFD:,:] -------
__global__ __launch_bounds__(256) void k_wt(
    const float* __restrict__ Wh, const float* __restrict__ Wo,
    bf16s* __restrict__ wt_h, bf16s* __restrict__ wt_o) {
  const float* S = blockIdx.x ? (Wo + AFD * H) : Wh;
  bf16s* D = blockIdx.x ? wt_o : wt_h;
  for (int i = threadIdx.x; i < H * H; i += 256) {
    int k = i >> 7, n = i & 127;
    D[n * H + k] = f2bf(S[i]);
  }
}

// Shared epilogue: 8 n-tile accumulators -> scalar bf16 C stores (merge in L2).
__device__ inline void store_cd(const f32x4 acc[8], bf16s* __restrict__ Pout,
                                int ebase, int m, int quad) {
  const int rbase = ebase + quad * 4;
#pragma unroll
  for (int nt = 0; nt < 8; ++nt) {
#pragma unroll
    for (int i = 0; i < 4; ++i) {
      Pout[(size_t)(rbase + i) * H + nt * 16 + m] = f2bf(acc[nt][i]);
    }
  }
}

// ---- binput = fbonds @ W_i (stored); P1 = relu(binput) @ W_h ----
// Register-direct A-frag: lane (m,quad) computes cols [kk*32+quad*8,+8) of
// edge ebase+m, stores binput, packs relu'd bf16 A-frag, MFMAs immediately.
// No LDS, no barriers.
__global__ __launch_bounds__(256) void k_binput_gemm(
    const float* __restrict__ fbonds, const float* __restrict__ Wi,
    const bf16s* __restrict__ wt_h, bf16s* __restrict__ binput,
    bf16s* __restrict__ P1) {
  const int tid = threadIdx.x;
  const int wave = tid >> 6;
  const int lane = tid & 63;
  const int m = lane & 15;
  const int quad = lane >> 4;
  const int ebase = (blockIdx.x * 4 + wave) * 16;
  const int e = ebase + m;

  float fb[INFD];
#pragma unroll
  for (int k = 0; k < INFD; ++k) fb[k] = fbonds[(size_t)e * INFD + k];

  f32x4 acc[8];
#pragma unroll
  for (int i = 0; i < 8; ++i) acc[i] = (f32x4){0.f, 0.f, 0.f, 0.f};
  const bf16s* Wp = wt_h + (size_t)m * H + quad * 8;

#pragma unroll 1
  for (int kk = 0; kk < 4; ++kk) {
    const int coff = kk * 32 + quad * 8;
    float s[8] = {0.f, 0.f, 0.f, 0.f, 0.f, 0.f, 0.f, 0.f};
#pragma unroll
    for (int k = 0; k < INFD; ++k) {
      float4 w0 = *(const float4*)&Wi[k * H + coff];
      float4 w1 = *(const float4*)&Wi[k * H + coff + 4];
      s[0] = fmaf(fb[k], w0.x, s[0]); s[1] = fmaf(fb[k], w0.y, s[1]);
      s[2] = fmaf(fb[k], w0.z, s[2]); s[3] = fmaf(fb[k], w0.w, s[3]);
      s[4] = fmaf(fb[k], w1.x, s[4]); s[5] = fmaf(fb[k], w1.y, s[5]);
      s[6] = fmaf(fb[k], w1.z, s[6]); s[7] = fmaf(fb[k], w1.w, s[7]);
    }
    ushort8v bq;
    short8 af;
#pragma unroll
    for (int i = 0; i < 8; ++i) {
      bq[i] = f2bf(s[i]);
      af[i] = (short)f2bf(fmaxf(s[i], 0.f));
    }
    *(ushort8v*)&binput[(size_t)e * H + coff] = bq;
#pragma unroll
    for (int nt = 0; nt < 8; ++nt) {
      short8 bfr = *(const short8*)(Wp + (size_t)(nt * 16) * H + kk * 32);
      acc[nt] = __builtin_amdgcn_mfma_f32_16x16x32_bf16(af, bfr, acc[nt], 0, 0, 0);
    }
  }
  store_cd(acc, P1, ebase, m, quad);
}

// ---- fused depth step: Pout = (relu(binput + sum_j P[bgraph[e][j]])) @ Wt ----
// Register-direct A-frag gather: lane (m,quad) gathers the 16-B column chunk
// of its edge's 15 neighbor rows per K-step, sums fp32, relu, packs bf16
// A-frag, issues that kk's 8 MFMAs. No LDS, no barriers; loads of kk+1
// overlap MFMAs of kk.
__global__ __launch_bounds__(256) void k_fused(
    const int* __restrict__ bgraph, const bf16s* __restrict__ P,
    const bf16s* __restrict__ binput, const bf16s* __restrict__ Wt,
    bf16s* __restrict__ Pout) {
  const int tid = threadIdx.x;
  const int wave = tid >> 6;
  const int lane = tid & 63;
  const int m = lane & 15;
  const int quad = lane >> 4;
  const int ebase = (blockIdx.x * 4 + wave) * 16;
  const int e = ebase + m;

  int idx[MAXNB];
#pragma unroll
  for (int j = 0; j < MAXNB; ++j) idx[j] = bgraph[(size_t)e * MAXNB + j];

  f32x4 acc[8];
#pragma unroll
  for (int i = 0; i < 8; ++i) acc[i] = (f32x4){0.f, 0.f, 0.f, 0.f};
  const bf16s* Wp = Wt + (size_t)m * H + quad * 8;

#pragma unroll 1
  for (int kk = 0; kk < 4; ++kk) {
    const int coff = kk * 32 + quad * 8;
    ushort8v t[MAXNB];
#pragma unroll
    for (int j = 0; j < MAXNB; ++j)
      t[j] = *(const ushort8v*)&P[(size_t)idx[j] * H + coff];
    ushort8v b = *(const ushort8v*)&binput[(size_t)e * H + coff];
    float s[8];
#pragma unroll
    for (int i = 0; i < 8; ++i) s[i] = bf2f(b[i]);
#pragma unroll
    for (int j = 0; j < MAXNB; ++j)
#pragma unroll
      for (int i = 0; i < 8; ++i) s[i] += bf2f(t[j][i]);
    short8 af;
#pragma unroll
    for (int i = 0; i < 8; ++i) af[i] = (short)f2bf(fmaxf(s[i], 0.f));
#pragma unroll
    for (int nt = 0; nt < 8; ++nt) {
      short8 bfr = *(const short8*)(Wp + (size_t)(nt * 16) * H + kk * 32);
      acc[nt] = __builtin_amdgcn_mfma_f32_16x16x32_bf16(af, bfr, acc[nt], 0, 0, 0);
    }
  }
  store_cd(acc, Pout, ebase, m, quad);
}

// atom_hiddens = relu(fatoms @ Wo[0:18] + sum_j msgWo[agraph[a][j]] + b_o)
__global__ __launch_bounds__(256) void k_atoms(
    const float* __restrict__ fatoms, const int* __restrict__ agraph,
    const bf16s* __restrict__ msgWo, const float* __restrict__ Wo,
    const float* __restrict__ bo, float* __restrict__ atomh) {
  __shared__ float Wl[AFD * H];
  const int tid = threadIdx.x;
  for (int i = tid; i < AFD * H; i += 256) Wl[i] = Wo[i];
  __syncthreads();
  const int lane = tid & 31;
  const int a = blockIdx.x * 8 + (tid >> 5);
  int idx[MAXNB];
#pragma unroll
  for (int j = 0; j < MAXNB; ++j) idx[j] = agraph[(size_t)a * MAXNB + j];
  ushort4 t[MAXNB];
#pragma unroll
  for (int j = 0; j < MAXNB; ++j)
    t[j] = *(const ushort4*)&msgWo[(size_t)idx[j] * H + lane * 4];
  float4 b = ((const float4*)bo)[lane];
  float acc[4] = {b.x, b.y, b.z, b.w};
#pragma unroll
  for (int k = 0; k < AFD; ++k) {
    float f = fatoms[(size_t)a * AFD + k];
    float4 w = *(const float4*)&Wl[k * H + lane * 4];
    acc[0] = fmaf(f, w.x, acc[0]); acc[1] = fmaf(f, w.y, acc[1]);
    acc[2] = fmaf(f, w.z, acc[2]); acc[3] = fmaf(f, w.w, acc[3]);
  }
#pragma unroll
  for (int j = 0; j < MAXNB; ++j) {
    acc[0] += bf2f(t[j].x); acc[1] += bf2f(t[j].y);
    acc[2] += bf2f(t[j].z); acc[3] += bf2f(t[j].w);
  }
  float r[4] = {fmaxf(acc[0], 0.f), fmaxf(acc[1], 0.f),
                fmaxf(acc[2], 0.f), fmaxf(acc[3], 0.f)};
  *(float4*)&atomh[(size_t)a * H + lane * 4] = make_float4(r[0], r[1], r[2], r[3]);
}

// ---------------- segment mean pool ----------------
__global__ void k_pool(const float* __restrict__ atomh,
                       const int* __restrict__ sstart, const int* __restrict__ slen,
                       float* __restrict__ out) {
  const int m = blockIdx.x;
  const int c = threadIdx.x;
  const int s = sstart[m];
  const int L = slen[m];
  float sum = 0.f;
  for (int i = 0; i < L; ++i) sum += atomh[(size_t)(s + i) * H + c];
  out[m * H + c] = sum / (float)L;
}

extern "C" void kernel_launch(void* const* d_in, const int* in_sizes, int n_in,
                              void* d_out, int out_size, void* d_ws, size_t ws_size,
                              hipStream_t stream) {
  const float* fatoms = (const float*)d_in[0];
  const float* fbonds = (const float*)d_in[1];
  const int* agraph = (const int*)d_in[2];
  const int* bgraph = (const int*)d_in[3];
  const int* sstart = (const int*)d_in[4];
  const int* slen = (const int*)d_in[5];
  const float* Wi = (const float*)d_in[6];
  const float* Wh = (const float*)d_in[7];
  const float* Wo = (const float*)d_in[8];
  const float* bo = (const float*)d_in[9];
  float* out = (float*)d_out;

  const size_t EH = (size_t)EDGES * H;
  bf16s* B0 = (bf16s*)d_ws;      // binput [E,H] bf16, 51.2 MB
  bf16s* B1 = B0 + EH;           // ping
  bf16s* B2 = B1 + EH;           // pong
  float* atomh = (float*)B0;     // overlays binput (dead after last fused step)
  bf16s* wt_h = (bf16s*)d_out;   // stashed in d_out; k_pool overwrites later
  bf16s* wt_o = wt_h + H * H;

  k_wt<<<2, 256, 0, stream>>>(Wh, Wo, wt_h, wt_o);
  k_binput_gemm<<<EDGES / 64, 256, 0, stream>>>(fbonds, Wi, wt_h, B0, B1);  // P1
  k_fused<<<EDGES / 64, 256, 0, stream>>>(bgraph, B1, B0, wt_h, B2);    // P2
  k_fused<<<EDGES / 64, 256, 0, stream>>>(bgraph, B2, B0, wt_h, B1);    // P3
  k_fused<<<EDGES / 64, 256, 0, stream>>>(bgraph, B1, B0, wt_h, B2);    // P4
  k_fused<<<EDGES / 64, 256, 0, stream>>>(bgraph, B2, B0, wt_h, B1);    // P5
  k_fused<<<EDGES / 64, 256, 0, stream>>>(bgraph, B1, B0, wt_o, B2);    // P6o
  k_atoms<<<NATOMS / 8, 256, 0, stream>>>(fatoms, agraph, B2, Wo, bo, atomh);
  k_pool<<<NMOLS, H, 0, stream>>>(atomh, sstart, slen, out);
}

// Round 13
// 1070.752 us; speedup vs baseline: 1.4310x; 1.4310x over previous
//
#include <hip/hip_runtime.h>

#define EDGES 200000
#define NATOMS 100000
#define NMOLS 2000
#define H 128
#define MAXNB 15
#define AFD 18
#define INFD 23

typedef unsigned short bf16s;
typedef __attribute__((ext_vector_type(8))) short short8;
typedef __attribute__((ext_vector_type(8))) unsigned short ushort8v;
typedef __attribute__((ext_vector_type(4))) float f32x4;

__device__ inline float bf2f(bf16s u) {
  union { unsigned int i; float f; } c; c.i = ((unsigned int)u) << 16; return c.f;
}
__device__ inline bf16s f2bf(float f) {
  union { float f; unsigned int i; } c; c.f = f;
  unsigned int lsb = (c.i >> 16) & 1u;
  c.i += 0x7fffu + lsb;              // round-to-nearest-even
  return (bf16s)(c.i >> 16);
}

// ------- one-time: Wt[n][k] = bf16(W[k][n]) for W_h and W_o[AFD:,:] -------
__global__ __launch_bounds__(256) void k_wt(
    const float* __restrict__ Wh, const float* __restrict__ Wo,
    bf16s* __restrict__ wt_h, bf16s* __restrict__ wt_o) {
  const float* S = blockIdx.x ? (Wo + AFD * H) : Wh;
  bf16s* D = blockIdx.x ? wt_o : wt_h;
  for (int i = threadIdx.x; i < H * H; i += 256) {
    int k = i >> 7, n = i & 127;
    D[n * H + k] = f2bf(S[i]);
  }
}

// Shared epilogue: 8 n-tile accumulators -> scalar bf16 C stores (merge in L2).
__device__ inline void store_cd(const f32x4 acc[8], bf16s* __restrict__ Pout,
                                int ebase, int m, int quad) {
  const int rbase = ebase + quad * 4;
#pragma unroll
  for (int nt = 0; nt < 8; ++nt) {
#pragma unroll
    for (int i = 0; i < 4; ++i) {
      Pout[(size_t)(rbase + i) * H + nt * 16 + m] = f2bf(acc[nt][i]);
    }
  }
}

// ---- binput = fbonds @ W_i (stored); P1 = relu(binput) @ W_h ----
// Register-direct, no LDS, no barriers (Wi is 11.8 KB -> L1-resident).
__global__ __launch_bounds__(256) void k_binput_gemm(
    const float* __restrict__ fbonds, const float* __restrict__ Wi,
    const bf16s* __restrict__ wt_h, bf16s* __restrict__ binput,
    bf16s* __restrict__ P1) {
  const int tid = threadIdx.x;
  const int wave = tid >> 6;
  const int lane = tid & 63;
  const int m = lane & 15;
  const int quad = lane >> 4;
  const int ebase = (blockIdx.x * 4 + wave) * 16;
  const int e = ebase + m;

  float fb[INFD];
#pragma unroll
  for (int k = 0; k < INFD; ++k) fb[k] = fbonds[(size_t)e * INFD + k];

  f32x4 acc[8];
#pragma unroll
  for (int i = 0; i < 8; ++i) acc[i] = (f32x4){0.f, 0.f, 0.f, 0.f};
  const bf16s* Wp = wt_h + (size_t)m * H + quad * 8;

#pragma unroll 1
  for (int kk = 0; kk < 4; ++kk) {
    const int coff = kk * 32 + quad * 8;
    float s[8] = {0.f, 0.f, 0.f, 0.f, 0.f, 0.f, 0.f, 0.f};
#pragma unroll
    for (int k = 0; k < INFD; ++k) {
      float4 w0 = *(const float4*)&Wi[k * H + coff];
      float4 w1 = *(const float4*)&Wi[k * H + coff + 4];
      s[0] = fmaf(fb[k], w0.x, s[0]); s[1] = fmaf(fb[k], w0.y, s[1]);
      s[2] = fmaf(fb[k], w0.z, s[2]); s[3] = fmaf(fb[k], w0.w, s[3]);
      s[4] = fmaf(fb[k], w1.x, s[4]); s[5] = fmaf(fb[k], w1.y, s[5]);
      s[6] = fmaf(fb[k], w1.z, s[6]); s[7] = fmaf(fb[k], w1.w, s[7]);
    }
    ushort8v bq;
    short8 af;
#pragma unroll
    for (int i = 0; i < 8; ++i) {
      bq[i] = f2bf(s[i]);
      af[i] = (short)f2bf(fmaxf(s[i], 0.f));
    }
    *(ushort8v*)&binput[(size_t)e * H + coff] = bq;
#pragma unroll
    for (int nt = 0; nt < 8; ++nt) {
      short8 bfr = *(const short8*)(Wp + (size_t)(nt * 16) * H + kk * 32);
      acc[nt] = __builtin_amdgcn_mfma_f32_16x16x32_bf16(af, bfr, acc[nt], 0, 0, 0);
    }
  }
  store_cd(acc, P1, ebase, m, quad);
}

// ---- fused depth step: Pout = (relu(binput + sum_j P[bgraph[e][j]])) @ Wt ----
// Register-direct single-pass gather: lane (m,quad) owns edge ebase+m and
// reads each neighbor row ONCE as 4x16B chunks in A-frag column order
// (cols kk*32+quad*8..+8, kk=0..3), accumulating into 32 fp32 regs. The 4
// quads of the wave jointly touch each row's full 256 B exactly once ->
// FETCH stays at the unique-row floor (R12's per-kk re-walk quadrupled it).
// No LDS, no barriers; row j+1 loads overlap row j accumulation.
__global__ __launch_bounds__(256) void k_fused(
    const int* __restrict__ bgraph, const bf16s* __restrict__ P,
    const bf16s* __restrict__ binput, const bf16s* __restrict__ Wt,
    bf16s* __restrict__ Pout) {
  const int tid = threadIdx.x;
  const int wave = tid >> 6;
  const int lane = tid & 63;
  const int m = lane & 15;
  const int quad = lane >> 4;
  const int ebase = (blockIdx.x * 4 + wave) * 16;
  const int e = ebase + m;

  int idx[MAXNB];
#pragma unroll
  for (int j = 0; j < MAXNB; ++j) idx[j] = bgraph[(size_t)e * MAXNB + j];

  // 32 fp32 column accumulators, init from binput (one-time 4x16B read)
  float s[4][8];
  {
    const bf16s* bp = &binput[(size_t)e * H + quad * 8];
#pragma unroll
    for (int kk = 0; kk < 4; ++kk) {
      ushort8v b = *(const ushort8v*)(bp + kk * 32);
#pragma unroll
      for (int i = 0; i < 8; ++i) s[kk][i] = bf2f(b[i]);
    }
  }
  // single pass over the 15 neighbor rows
#pragma unroll
  for (int j = 0; j < MAXNB; ++j) {
    const bf16s* rp = &P[(size_t)idx[j] * H + quad * 8];
    ushort8v t0 = *(const ushort8v*)(rp);
    ushort8v t1 = *(const ushort8v*)(rp + 32);
    ushort8v t2 = *(const ushort8v*)(rp + 64);
    ushort8v t3 = *(const ushort8v*)(rp + 96);
#pragma unroll
    for (int i = 0; i < 8; ++i) {
      s[0][i] += bf2f(t0[i]); s[1][i] += bf2f(t1[i]);
      s[2][i] += bf2f(t2[i]); s[3][i] += bf2f(t3[i]);
    }
  }

  // MFMA phase from registers
  f32x4 acc[8];
#pragma unroll
  for (int i = 0; i < 8; ++i) acc[i] = (f32x4){0.f, 0.f, 0.f, 0.f};
  const bf16s* Wp = Wt + (size_t)m * H + quad * 8;
#pragma unroll
  for (int kk = 0; kk < 4; ++kk) {
    short8 af;
#pragma unroll
    for (int i = 0; i < 8; ++i) af[i] = (short)f2bf(fmaxf(s[kk][i], 0.f));
#pragma unroll
    for (int nt = 0; nt < 8; ++nt) {
      short8 bfr = *(const short8*)(Wp + (size_t)(nt * 16) * H + kk * 32);
      acc[nt] = __builtin_amdgcn_mfma_f32_16x16x32_bf16(af, bfr, acc[nt], 0, 0, 0);
    }
  }
  store_cd(acc, Pout, ebase, m, quad);
}

// atom_hiddens = relu(fatoms @ Wo[0:18] + sum_j msgWo[agraph[a][j]] + b_o)
__global__ __launch_bounds__(256) void k_atoms(
    const float* __restrict__ fatoms, const int* __restrict__ agraph,
    const bf16s* __restrict__ msgWo, const float* __restrict__ Wo,
    const float* __restrict__ bo, float* __restrict__ atomh) {
  __shared__ float Wl[AFD * H];
  const int tid = threadIdx.x;
  for (int i = tid; i < AFD * H; i += 256) Wl[i] = Wo[i];
  __syncthreads();
  const int lane = tid & 31;
  const int a = blockIdx.x * 8 + (tid >> 5);
  int idx[MAXNB];
#pragma unroll
  for (int j = 0; j < MAXNB; ++j) idx[j] = agraph[(size_t)a * MAXNB + j];
  ushort4 t[MAXNB];
#pragma unroll
  for (int j = 0; j < MAXNB; ++j)
    t[j] = *(const ushort4*)&msgWo[(size_t)idx[j] * H + lane * 4];
  float4 b = ((const float4*)bo)[lane];
  float acc[4] = {b.x, b.y, b.z, b.w};
#pragma unroll
  for (int k = 0; k < AFD; ++k) {
    float f = fatoms[(size_t)a * AFD + k];
    float4 w = *(const float4*)&Wl[k * H + lane * 4];
    acc[0] = fmaf(f, w.x, acc[0]); acc[1] = fmaf(f, w.y, acc[1]);
    acc[2] = fmaf(f, w.z, acc[2]); acc[3] = fmaf(f, w.w, acc[3]);
  }
#pragma unroll
  for (int j = 0; j < MAXNB; ++j) {
    acc[0] += bf2f(t[j].x); acc[1] += bf2f(t[j].y);
    acc[2] += bf2f(t[j].z); acc[3] += bf2f(t[j].w);
  }
  float r[4] = {fmaxf(acc[0], 0.f), fmaxf(acc[1], 0.f),
                fmaxf(acc[2], 0.f), fmaxf(acc[3], 0.f)};
  *(float4*)&atomh[(size_t)a * H + lane * 4] = make_float4(r[0], r[1], r[2], r[3]);
}

// ---------------- segment mean pool ----------------
__global__ void k_pool(const float* __restrict__ atomh,
                       const int* __restrict__ sstart, const int* __restrict__ slen,
                       float* __restrict__ out) {
  const int m = blockIdx.x;
  const int c = threadIdx.x;
  const int s = sstart[m];
  const int L = slen[m];
  float sum = 0.f;
  for (int i = 0; i < L; ++i) sum += atomh[(size_t)(s + i) * H + c];
  out[m * H + c] = sum / (float)L;
}

extern "C" void kernel_launch(void* const* d_in, const int* in_sizes, int n_in,
                              void* d_out, int out_size, void* d_ws, size_t ws_size,
                              hipStream_t stream) {
  const float* fatoms = (const float*)d_in[0];
  const float* fbonds = (const float*)d_in[1];
  const int* agraph = (const int*)d_in[2];
  const int* bgraph = (const int*)d_in[3];
  const int* sstart = (const int*)d_in[4];
  const int* slen = (const int*)d_in[5];
  const float* Wi = (const float*)d_in[6];
  const float* Wh = (const float*)d_in[7];
  const float* Wo = (const float*)d_in[8];
  const float* bo = (const float*)d_in[9];
  float* out = (float*)d_out;

  const size_t EH = (size_t)EDGES * H;
  bf16s* B0 = (bf16s*)d_ws;      // binput [E,H] bf16, 51.2 MB
  bf16s* B1 = B0 + EH;           // ping
  bf16s* B2 = B1 + EH;           // pong
  float* atomh = (float*)B0;     // overlays binput (dead after last fused step)
  bf16s* wt_h = (bf16s*)d_out;   // stashed in d_out; k_pool overwrites later
  bf16s* wt_o = wt_h + H * H;

  k_wt<<<2, 256, 0, stream>>>(Wh, Wo, wt_h, wt_o);
  k_binput_gemm<<<EDGES / 64, 256, 0, stream>>>(fbonds, Wi, wt_h, B0, B1);  // P1
  k_fused<<<EDGES / 64, 256, 0, stream>>>(bgraph, B1, B0, wt_h, B2);    // P2
  k_fused<<<EDGES / 64, 256, 0, stream>>>(bgraph, B2, B0, wt_h, B1);    // P3
  k_fused<<<EDGES / 64, 256, 0, stream>>>(bgraph, B1, B0, wt_h, B2);    // P4
  k_fused<<<EDGES / 64, 256, 0, stream>>>(bgraph, B2, B0, wt_h, B1);    // P5
  k_fused<<<EDGES / 64, 256, 0, stream>>>(bgraph, B1, B0, wt_o, B2);    // P6o
  k_atoms<<<NATOMS / 8, 256, 0, stream>>>(fatoms, agraph, B2, Wo, bo, atomh);
  k_pool<<<NMOLS, H, 0, stream>>>(atomh, sstart, slen, out);
}

// Round 14
// 918.103 us; speedup vs baseline: 1.6689x; 1.1663x over previous
//
#include <hip/hip_runtime.h>

#define EDGES 200000
#define NATOMS 100000
#define NMOLS 2000
#define H 128
#define MAXNB 15
#define AFD 18
#define INFD 23
#define LROW 136  // LDS A-tile row stride (bf16): +8 pad, 16B-aligned rows, 2-way banks

typedef unsigned short bf16s;
typedef __attribute__((ext_vector_type(8))) short short8;
typedef __attribute__((ext_vector_type(4))) float f32x4;

__device__ inline float bf2f(bf16s u) {
  union { unsigned int i; float f; } c; c.i = ((unsigned int)u) << 16; return c.f;
}
__device__ inline bf16s f2bf(float f) {
  union { float f; unsigned int i; } c; c.f = f;
  unsigned int lsb = (c.i >> 16) & 1u;
  c.i += 0x7fffu + lsb;              // round-to-nearest-even
  return (bf16s)(c.i >> 16);
}
__device__ inline void load4(const bf16s* p, float v[4]) {
  ushort4 t = *(const ushort4*)p;
  v[0] = bf2f(t.x); v[1] = bf2f(t.y); v[2] = bf2f(t.z); v[3] = bf2f(t.w);
}
__device__ inline void store4(bf16s* p, const float v[4]) {
  ushort4 t; t.x = f2bf(v[0]); t.y = f2bf(v[1]); t.z = f2bf(v[2]); t.w = f2bf(v[3]);
  *(ushort4*)p = t;
}

// ------- one-time: Wt[n][k] = bf16(W[k][n]) for W_h and W_o[AFD:,:] -------
__global__ __launch_bounds__(256) void k_wt(
    const float* __restrict__ Wh, const float* __restrict__ Wo,
    bf16s* __restrict__ wt_h, bf16s* __restrict__ wt_o) {
  const float* S = blockIdx.x ? (Wo + AFD * H) : Wh;
  bf16s* D = blockIdx.x ? wt_o : wt_h;
  for (int i = threadIdx.x; i < H * H; i += 256) {
    int k = i >> 7, n = i & 127;
    D[n * H + k] = f2bf(S[i]);
  }
}

// Two-pass MFMA epilogue: 16x128 @ 128x128 from wave-private LDS tile.
__device__ inline void mfma_two_pass(const bf16s* Aw, const bf16s* __restrict__ Wt,
                                     bf16s* __restrict__ Pout, int ebase, int lane) {
  const int mm = lane & 15;
  const int quad = lane >> 4;
  const bf16s* Wp = Wt + (size_t)mm * H + quad * 8;
  const int rbase = ebase + quad * 4;
#pragma unroll 1
  for (int half = 0; half < 2; ++half) {
    f32x4 acc[4];
#pragma unroll
    for (int i = 0; i < 4; ++i) acc[i] = (f32x4){0.f, 0.f, 0.f, 0.f};
#pragma unroll
    for (int kk = 0; kk < 4; ++kk) {
      short8 af = *(const short8*)&Aw[mm * LROW + quad * 8 + kk * 32];
#pragma unroll
      for (int nt = 0; nt < 4; ++nt) {
        short8 bfr = *(const short8*)(Wp + (size_t)((half * 4 + nt) * 16) * H + kk * 32);
        acc[nt] = __builtin_amdgcn_mfma_f32_16x16x32_bf16(af, bfr, acc[nt], 0, 0, 0);
      }
    }
#pragma unroll
    for (int nt = 0; nt < 4; ++nt) {
#pragma unroll
      for (int i = 0; i < 4; ++i) {
        Pout[(size_t)(rbase + i) * H + (half * 4 + nt) * 16 + mm] = f2bf(acc[nt][i]);
      }
    }
  }
}

// ---- binput = fbonds @ W_i (stored); P1 = relu(binput) @ W_h ----
// 2-wave blocks, wave-private, no LDS weight copy (Wi is 11.8 KB, L1-resident),
// no __syncthreads.
__global__ __launch_bounds__(128) void k_binput_gemm(
    const float* __restrict__ fbonds, const float* __restrict__ Wi,
    const bf16s* __restrict__ wt_h, bf16s* __restrict__ binput,
    bf16s* __restrict__ P1) {
  __shared__ bf16s Am[2][16 * LROW];
  const int tid = threadIdx.x;
  const int wave = tid >> 6;
  const int lane = tid & 63;
  bf16s* Aw = Am[wave];
  const int ebase = (blockIdx.x * 2 + wave) * 16;
  const int sub = lane >> 5;
  const int col = lane & 31;
  for (int r = 0; r < 8; ++r) {
    const int erow = r * 2 + sub;
    const int e = ebase + erow;
    const float* fb = &fbonds[(size_t)e * INFD];
    float acc[4] = {0.f, 0.f, 0.f, 0.f};
#pragma unroll
    for (int k = 0; k < INFD; ++k) {
      float f = fb[k];
      float4 w = *(const float4*)&Wi[k * H + col * 4];
      acc[0] = fmaf(f, w.x, acc[0]); acc[1] = fmaf(f, w.y, acc[1]);
      acc[2] = fmaf(f, w.z, acc[2]); acc[3] = fmaf(f, w.w, acc[3]);
    }
    store4(&binput[(size_t)e * H + col * 4], acc);
    ushort4 mq;
    mq.x = f2bf(fmaxf(acc[0], 0.f)); mq.y = f2bf(fmaxf(acc[1], 0.f));
    mq.z = f2bf(fmaxf(acc[2], 0.f)); mq.w = f2bf(fmaxf(acc[3], 0.f));
    *(ushort4*)&Aw[erow * LROW + col * 4] = mq;
  }
  asm volatile("s_waitcnt lgkmcnt(0)" ::: "memory");
  mfma_two_pass(Aw, wt_h, P1, ebase, lane);
}

// ---- fused depth step: Pout = (relu(binput + sum_j P[bgraph[e][j]])) @ Wt ----
// R10 form: 2-wave blocks, wave-private LDS, no block barrier, no prefetch.
__global__ __launch_bounds__(128) void k_fused(
    const int* __restrict__ bgraph, const bf16s* __restrict__ P,
    const bf16s* __restrict__ binput, const bf16s* __restrict__ Wt,
    bf16s* __restrict__ Pout) {
  __shared__ bf16s Am[2][16 * LROW];
  const int tid = threadIdx.x;
  const int wave = tid >> 6;
  const int lane = tid & 63;
  bf16s* Aw = Am[wave];
  const int ebase = (blockIdx.x * 2 + wave) * 16;

  const int sub = lane >> 5;
  const int col = lane & 31;
  for (int r = 0; r < 8; ++r) {
    const int erow = r * 2 + sub;
    const int e = ebase + erow;
    int idx[MAXNB];
#pragma unroll
    for (int j = 0; j < MAXNB; ++j) idx[j] = bgraph[(size_t)e * MAXNB + j];
    ushort4 t[MAXNB];
#pragma unroll
    for (int j = 0; j < MAXNB; ++j)
      t[j] = *(const ushort4*)&P[(size_t)idx[j] * H + col * 4];
    float acc[4];
    load4(&binput[(size_t)e * H + col * 4], acc);
#pragma unroll
    for (int j = 0; j < MAXNB; ++j) {
      acc[0] += bf2f(t[j].x); acc[1] += bf2f(t[j].y);
      acc[2] += bf2f(t[j].z); acc[3] += bf2f(t[j].w);
    }
    ushort4 mq;
    mq.x = f2bf(fmaxf(acc[0], 0.f)); mq.y = f2bf(fmaxf(acc[1], 0.f));
    mq.z = f2bf(fmaxf(acc[2], 0.f)); mq.w = f2bf(fmaxf(acc[3], 0.f));
    *(ushort4*)&Aw[erow * LROW + col * 4] = mq;
  }
  asm volatile("s_waitcnt lgkmcnt(0)" ::: "memory");
  mfma_two_pass(Aw, Wt, Pout, ebase, lane);
}

// atom_hiddens = relu(fatoms @ Wo[0:18] + sum_j msgWo[agraph[a][j]] + b_o)
__global__ __launch_bounds__(256) void k_atoms(
    const float* __restrict__ fatoms, const int* __restrict__ agraph,
    const bf16s* __restrict__ msgWo, const float* __restrict__ Wo,
    const float* __restrict__ bo, float* __restrict__ atomh) {
  __shared__ float Wl[AFD * H];
  const int tid = threadIdx.x;
  for (int i = tid; i < AFD * H; i += 256) Wl[i] = Wo[i];
  __syncthreads();
  const int lane = tid & 31;
  const int a = blockIdx.x * 8 + (tid >> 5);
  int idx[MAXNB];
#pragma unroll
  for (int j = 0; j < MAXNB; ++j) idx[j] = agraph[(size_t)a * MAXNB + j];
  ushort4 t[MAXNB];
#pragma unroll
  for (int j = 0; j < MAXNB; ++j)
    t[j] = *(const ushort4*)&msgWo[(size_t)idx[j] * H + lane * 4];
  float4 b = ((const float4*)bo)[lane];
  float acc[4] = {b.x, b.y, b.z, b.w};
#pragma unroll
  for (int k = 0; k < AFD; ++k) {
    float f = fatoms[(size_t)a * AFD + k];
    float4 w = *(const float4*)&Wl[k * H + lane * 4];
    acc[0] = fmaf(f, w.x, acc[0]); acc[1] = fmaf(f, w.y, acc[1]);
    acc[2] = fmaf(f, w.z, acc[2]); acc[3] = fmaf(f, w.w, acc[3]);
  }
#pragma unroll
  for (int j = 0; j < MAXNB; ++j) {
    acc[0] += bf2f(t[j].x); acc[1] += bf2f(t[j].y);
    acc[2] += bf2f(t[j].z); acc[3] += bf2f(t[j].w);
  }
  float r[4] = {fmaxf(acc[0], 0.f), fmaxf(acc[1], 0.f),
                fmaxf(acc[2], 0.f), fmaxf(acc[3], 0.f)};
  *(float4*)&atomh[(size_t)a * H + lane * 4] = make_float4(r[0], r[1], r[2], r[3]);
}

// ---------------- segment mean pool ----------------
__global__ void k_pool(const float* __restrict__ atomh,
                       const int* __restrict__ sstart, const int* __restrict__ slen,
                       float* __restrict__ out) {
  const int m = blockIdx.x;
  const int c = threadIdx.x;
  const int s = sstart[m];
  const int L = slen[m];
  float sum = 0.f;
  for (int i = 0; i < L; ++i) sum += atomh[(size_t)(s + i) * H + c];
  out[m * H + c] = sum / (float)L;
}

extern "C" void kernel_launch(void* const* d_in, const int* in_sizes, int n_in,
                              void* d_out, int out_size, void* d_ws, size_t ws_size,
                              hipStream_t stream) {
  const float* fatoms = (const float*)d_in[0];
  const float* fbonds = (const float*)d_in[1];
  const int* agraph = (const int*)d_in[2];
  const int* bgraph = (const int*)d_in[3];
  const int* sstart = (const int*)d_in[4];
  const int* slen = (const int*)d_in[5];
  const float* Wi = (const float*)d_in[6];
  const float* Wh = (const float*)d_in[7];
  const float* Wo = (const float*)d_in[8];
  const float* bo = (const float*)d_in[9];
  float* out = (float*)d_out;

  const size_t EH = (size_t)EDGES * H;
  bf16s* B0 = (bf16s*)d_ws;      // binput [E,H] bf16, 51.2 MB
  bf16s* B1 = B0 + EH;           // ping
  bf16s* B2 = B1 + EH;           // pong
  float* atomh = (float*)B0;     // overlays binput (dead after last fused step)
  bf16s* wt_h = (bf16s*)d_out;   // stashed in d_out; k_pool overwrites later
  bf16s* wt_o = wt_h + H * H;

  k_wt<<<2, 256, 0, stream>>>(Wh, Wo, wt_h, wt_o);
  k_binput_gemm<<<EDGES / 32, 128, 0, stream>>>(fbonds, Wi, wt_h, B0, B1);  // P1
  k_fused<<<EDGES / 32, 128, 0, stream>>>(bgraph, B1, B0, wt_h, B2);    // P2
  k_fused<<<EDGES / 32, 128, 0, stream>>>(bgraph, B2, B0, wt_h, B1);    // P3
  k_fused<<<EDGES / 32, 128, 0, stream>>>(bgraph, B1, B0, wt_h, B2);    // P4
  k_fused<<<EDGES / 32, 128, 0, stream>>>(bgraph, B2, B0, wt_h, B1);    // P5
  k_fused<<<EDGES / 32, 128, 0, stream>>>(bgraph, B1, B0, wt_o, B2);    // P6o
  k_atoms<<<NATOMS / 8, 256, 0, stream>>>(fatoms, agraph, B2, Wo, bo, atomh);
  k_pool<<<NMOLS, H, 0, stream>>>(atomh, sstart, slen, out);
}